// Round 4
// baseline (161.016 us; speedup 1.0000x reference)
//
#include <hip/hip_runtime.h>

typedef float  f32x4  __attribute__((ext_vector_type(4)));
typedef __bf16 bf16x8 __attribute__((ext_vector_type(8)));
typedef unsigned short u16x8 __attribute__((ext_vector_type(8)));

#define NB 32
#define NC 256
#define NHW 4096                  // 64*64
#define NN (NB*NHW)               // 131072 rows
#define NK 1024                   // codes
#define NUMEL ((size_t)NN*NC)     // 33554432
#define BM 64                     // rows per block
#define NBLK (NN/BM)              // 2048 blocks
#define QTS 260                   // Qt row stride (floats), 16B-aligned

static __device__ __forceinline__ unsigned short f2bf(float f) {
    unsigned u = __builtin_bit_cast(unsigned, f);
    return (unsigned short)((u + 0x7fffu + ((u >> 16) & 1u)) >> 16);
}

// ---------- prepack emb fp32 -> fragment-linear bf16 ----------
// off = [ch 4b][cgp 2b][ds 3b][g 2b][col 4b][j 3b]
// code = ch*64 + cgp*16 + col ; k = ds*32 + g*8 + j
__global__ void vq_prepack(const float* __restrict__ emb, unsigned short* __restrict__ packed) {
    const int off = blockIdx.x * 256 + threadIdx.x;   // 0..262143
    const int j   = off & 7;
    const int col = (off >> 3) & 15;
    const int g   = (off >> 7) & 3;
    const int ds  = (off >> 9) & 7;
    const int cgp = (off >> 12) & 3;
    const int ch  = off >> 14;
    const int code = ch * 64 + cgp * 16 + col;
    const int k    = ds * 32 + g * 8 + j;
    packed[off] = f2bf(emb[code * NC + k]);
}

// ---------- e_norm ----------
__global__ void vq_enorm(const float* __restrict__ emb, float* __restrict__ enorm) {
    int k = blockIdx.x * 256 + threadIdx.x;
    if (k >= NK) return;
    const float4* row = (const float4*)(emb + (size_t)k * NC);
    float s = 0.f;
#pragma unroll
    for (int i = 0; i < NC / 4; ++i) {
        float4 v = row[i];
        s = fmaf(v.x, v.x, fmaf(v.y, v.y, fmaf(v.z, v.z, fmaf(v.w, v.w, s))));
    }
    enorm[k] = s;
}

// prefetch one chunk's B-fragments (16 codes x K=256) straight from L2 into regs
#define PREFETCH(BUF, CH) do {                                                 \
    const unsigned short* gp = packed + ((((CH) << 2) + wv) << 12) + (lane << 3); \
    _Pragma("unroll")                                                          \
    for (int ds_ = 0; ds_ < 8; ++ds_)                                          \
        BUF[ds_] = *(const bf16x8*)(gp + (ds_ << 9));                          \
} while (0)

#define COMPUTE(BUF, CH) do {                                                  \
    f32x4 ac0 = {0.f,0.f,0.f,0.f}, ac1 = {0.f,0.f,0.f,0.f};                    \
    f32x4 ac2 = {0.f,0.f,0.f,0.f}, ac3 = {0.f,0.f,0.f,0.f};                    \
    _Pragma("unroll")                                                          \
    for (int ds_ = 0; ds_ < 8; ++ds_) {                                        \
        ac0 = __builtin_amdgcn_mfma_f32_16x16x32_bf16(af[0][ds_], BUF[ds_], ac0, 0, 0, 0); \
        ac1 = __builtin_amdgcn_mfma_f32_16x16x32_bf16(af[1][ds_], BUF[ds_], ac1, 0, 0, 0); \
        ac2 = __builtin_amdgcn_mfma_f32_16x16x32_bf16(af[2][ds_], BUF[ds_], ac2, 0, 0, 0); \
        ac3 = __builtin_amdgcn_mfma_f32_16x16x32_bf16(af[3][ds_], BUF[ds_], ac3, 0, 0, 0); \
    }                                                                          \
    const int ch_ = (CH);                                                      \
    const float en = enl[(ch_ << 6) + (wv << 4) + col];                        \
    _Pragma("unroll")                                                          \
    for (int q = 0; q < 4; ++q) {                                              \
        float d0 = fmaf(-2.f, ac0[q], en);                                     \
        float d1 = fmaf(-2.f, ac1[q], en);                                     \
        float d2 = fmaf(-2.f, ac2[q], en);                                     \
        float d3 = fmaf(-2.f, ac3[q], en);                                     \
        bool c0 = d0 < bestv[0][q], c1 = d1 < bestv[1][q];                     \
        bool c2 = d2 < bestv[2][q], c3 = d3 < bestv[3][q];                     \
        unsigned n0 = (bestc[0] & ~(0xFFu << (8*q))) | ((unsigned)ch_ << (8*q)); \
        unsigned n1 = (bestc[1] & ~(0xFFu << (8*q))) | ((unsigned)ch_ << (8*q)); \
        unsigned n2 = (bestc[2] & ~(0xFFu << (8*q))) | ((unsigned)ch_ << (8*q)); \
        unsigned n3 = (bestc[3] & ~(0xFFu << (8*q))) | ((unsigned)ch_ << (8*q)); \
        bestv[0][q] = c0 ? d0 : bestv[0][q];  bestc[0] = c0 ? n0 : bestc[0];   \
        bestv[1][q] = c1 ? d1 : bestv[1][q];  bestc[1] = c1 ? n1 : bestc[1];   \
        bestv[2][q] = c2 ? d2 : bestv[2][q];  bestc[2] = c2 ? n2 : bestc[2];   \
        bestv[3][q] = c3 ? d3 : bestv[3][q];  bestc[3] = c3 ? n3 : bestc[3];   \
    }                                                                          \
} while (0)

// ---------- main ----------
__global__ __launch_bounds__(256, 2)
void vq_main(const float* __restrict__ x, const float* __restrict__ emb,
             const unsigned short* __restrict__ packed, const float* __restrict__ enorm_g,
             float* __restrict__ out, float* __restrict__ partials)
{
    __shared__ __align__(16) char LDS[66848];
    unsigned short* Xb   = (unsigned short*)LDS;        // [c 256][r 64] bf16 XOR-swz, 32 KiB
    float*          enl  = (float*)(LDS + 32768);       // [1024], 4 KiB
    float*          redv = (float*)(LDS + 36864);       // [4][64]
    int*            redi = (int*)(LDS + 37888);         // [4][64]
    float*          Qt   = (float*)LDS;                 // [64][260] fp32 overlay
    int*            widx = (int*)(LDS + 66560);         // [64]
    float*          wsum = (float*)(LDS + 66816);       // [4]

    const int tid  = threadIdx.x;
    const int blk  = blockIdx.x;
    const int b    = blk >> 6;                 // 64 tiles of 64 hw per image
    const int hw0  = (blk & 63) << 6;
    const int wv   = tid >> 6;                 // wave = code-group (4 x 16 codes)
    const int lane = tid & 63;
    const int col  = lane & 15;
    const int g    = lane >> 4;

    // ---- stage x -> Xb[c][r] (XOR-swizzled) + sum x^2 ----
    float xsq = 0.f;
    {
        const int rq = tid & 15;
        const int cb = tid >> 4;               // 0..15
        const int r4 = rq << 2;
#pragma unroll
        for (int it = 0; it < 16; ++it) {
            const int c = cb + (it << 4);
            const float4 v = *(const float4*)(x + (size_t)(b * NC + c) * NHW + hw0 + r4);
            xsq = fmaf(v.x, v.x, fmaf(v.y, v.y, fmaf(v.z, v.z, fmaf(v.w, v.w, xsq))));
            ushort4 h = {f2bf(v.x), f2bf(v.y), f2bf(v.z), f2bf(v.w)};
            *(ushort4*)&Xb[((c << 6) + r4) ^ (((c >> 3) & 3) << 4)] = h;
        }
    }
    *(float4*)&enl[tid << 2] = *(const float4*)&enorm_g[tid << 2];
#pragma unroll
    for (int o = 32; o > 0; o >>= 1) xsq += __shfl_down(xsq, o, 64);
    if (lane == 0) wsum[wv] = xsq;
    __syncthreads();   // Xb + enl visible

    // ---- prefetch chunk 0 B-frags (regs), then A-frags from Xb ----
    bf16x8 b0[8], b1[8];
    PREFETCH(b0, 0);

    bf16x8 af[4][8];   // 4 M-tiles (all 64 rows) x 8 k-steps: 128 VGPR
#pragma unroll
    for (int mt = 0; mt < 4; ++mt)
#pragma unroll
        for (int ds = 0; ds < 8; ++ds) {
            u16x8 t;
#pragma unroll
            for (int j = 0; j < 8; ++j)
                t[j] = Xb[((((ds << 5) + (g << 3) + j) << 6) + (mt << 4) + col) ^ (g << 4)];
            af[mt][ds] = __builtin_bit_cast(bf16x8, t);
        }

    float    bestv[4][4];
    unsigned bestc[4];
#pragma unroll
    for (int mt = 0; mt < 4; ++mt) {
        bestc[mt] = 0u;
#pragma unroll
        for (int q = 0; q < 4; ++q) bestv[mt][q] = 3.4e38f;
    }

    // ---- 16-chunk K-loop: no LDS staging, no barriers, reg double-buffer ----
    for (int p = 0; p < 8; ++p) {
        const int c0 = p << 1;
        PREFETCH(b1, c0 + 1);
        COMPUTE(b0, c0);
        if (p < 7) PREFETCH(b0, c0 + 2);
        COMPUTE(b1, c0 + 1);
    }

    // ---- reconstruct indices, cross-lane argmin over 16 col-lanes ----
    int besti[4][4];
#pragma unroll
    for (int mt = 0; mt < 4; ++mt)
#pragma unroll
        for (int q = 0; q < 4; ++q)
            besti[mt][q] = (int)(((bestc[mt] >> (8 * q)) & 255u) << 6) + (wv << 4) + col;
#pragma unroll
    for (int m = 1; m <= 8; m <<= 1) {
#pragma unroll
        for (int mt = 0; mt < 4; ++mt)
#pragma unroll
            for (int q = 0; q < 4; ++q) {
                const float ov = __shfl_xor(bestv[mt][q], m, 64);
                const int   oi = __shfl_xor(besti[mt][q], m, 64);
                if (ov < bestv[mt][q] || (ov == bestv[mt][q] && oi < besti[mt][q])) {
                    bestv[mt][q] = ov; besti[mt][q] = oi;
                }
            }
    }

    // ---- cross-wave argmin (4 code-group waves) + loss partial ----
    if (col == 0) {
#pragma unroll
        for (int mt = 0; mt < 4; ++mt)
#pragma unroll
            for (int q = 0; q < 4; ++q) {
                const int r = (mt << 4) + (g << 2) + q;
                redv[(wv << 6) + r] = bestv[mt][q];
                redi[(wv << 6) + r] = besti[mt][q];
            }
    }
    __syncthreads();
    if (tid < 64) {
        float bv = redv[tid]; int bi = redi[tid];
#pragma unroll
        for (int w = 1; w < 4; ++w) {
            const float v = redv[(w << 6) + tid];
            const int   i = redi[(w << 6) + tid];
            if (v < bv || (v == bv && i < bi)) { bv = v; bi = i; }
        }
        widx[tid] = bi;
        float bsum = bv;   // min dist = ||e||^2 - 2 x.e
#pragma unroll
        for (int o = 32; o > 0; o >>= 1) bsum += __shfl_down(bsum, o, 64);
        if (tid == 0)
            partials[blk] = bsum + wsum[0] + wsum[1] + wsum[2] + wsum[3];  // + sum x^2
    }
    __syncthreads();   // widx ready; all waves past loop -> Qt may overwrite Xb/enl/red

    // ---- gather e-rows coalesced -> Qt fp32 (exact), transposed write-out ----
#pragma unroll
    for (int rr = 0; rr < 16; ++rr) {
        const int r  = (wv << 4) + rr;
        const int ki = widx[r];                         // wave-uniform broadcast
        const float4 ev = *(const float4*)(emb + (size_t)ki * NC + (lane << 2));
        *(float4*)&Qt[r * QTS + (lane << 2)] = ev;
    }
    __syncthreads();
    {
        const int rq = lane & 15;
        const int cq = lane >> 4;
#pragma unroll
        for (int cc = 0; cc < 16; ++cc) {
            const int c = (wv << 6) + (cc << 2) + cq;
            const size_t obase = (size_t)(b * NC + c) * NHW + hw0;
#pragma unroll
            for (int q = 0; q < 4; ++q) {
                const int r = rq + (q << 4);
                out[obase + r] = Qt[r * QTS + c];
            }
        }
    }
}

// ---------- final loss reduction ----------
__global__ void vq_loss_final(const float* __restrict__ partials, float* __restrict__ out_loss) {
    __shared__ float sdata[256];
    float s = 0.f;
    for (int i = threadIdx.x; i < NBLK; i += 256) s += partials[i];
    sdata[threadIdx.x] = s;
    __syncthreads();
    for (int off = 128; off > 0; off >>= 1) {
        if (threadIdx.x < off) sdata[threadIdx.x] += sdata[threadIdx.x + off];
        __syncthreads();
    }
    if (threadIdx.x == 0)
        out_loss[0] = 1.25f * sdata[0] / (float)NUMEL;
}

extern "C" void kernel_launch(void* const* d_in, const int* in_sizes, int n_in,
                              void* d_out, int out_size, void* d_ws, size_t ws_size,
                              hipStream_t stream) {
    const float* x   = (const float*)d_in[0];
    const float* emb = (const float*)d_in[1];
    float* out = (float*)d_out;                              // [NUMEL] quantized + [1] loss
    char*  ws  = (char*)d_ws;
    float* partials = (float*)ws;                            // 2048 floats @ 0
    float* enorm    = (float*)(ws + 8192);                   // 1024 floats
    unsigned short* packed = (unsigned short*)(ws + 12288);  // 512 KiB frag-packed emb

    hipLaunchKernelGGL(vq_prepack, dim3(NK * NC / 256), dim3(256), 0, stream, emb, packed);
    hipLaunchKernelGGL(vq_enorm, dim3(NK / 256), dim3(256), 0, stream, emb, enorm);
    hipLaunchKernelGGL(vq_main, dim3(NBLK), dim3(256), 0, stream, x, emb, packed, enorm, out, partials);
    hipLaunchKernelGGL(vq_loss_final, dim3(1), dim3(256), 0, stream, partials, out + NUMEL);
}

// Round 5
// 155.708 us; speedup vs baseline: 1.0341x; 1.0341x over previous
//
#include <hip/hip_runtime.h>

typedef float  f32x4  __attribute__((ext_vector_type(4)));
typedef __bf16 bf16x8 __attribute__((ext_vector_type(8)));
typedef unsigned short u16x8 __attribute__((ext_vector_type(8)));

#define NB 32
#define NC 256
#define NHW 4096                  // 64*64
#define NN (NB*NHW)               // 131072 rows
#define NK 1024                   // codes
#define NUMEL ((size_t)NN*NC)     // 33554432
#define BM 64                     // rows per block
#define NBLK (NN/BM)              // 2048 blocks
#define NCHUNK 16                 // 64 codes per chunk
#define CH_SHORTS 16384           // 64 codes * 256 k
#define QTS 258                   // Qt row stride (floats): %32=2 -> 4-way read, float2-aligned

static __device__ __forceinline__ unsigned short f2bf(float f) {
    unsigned u = __builtin_bit_cast(unsigned, f);
    return (unsigned short)((u + 0x7fffu + ((u >> 16) & 1u)) >> 16);
}

// ---------- prepack emb fp32 -> fragment-linear bf16 ----------
// off = [ch 4b][cgp 2b][ds 3b][g 2b][col 4b][j 3b]
// code = ch*64 + cgp*16 + col ; k = ds*32 + g*8 + j
__global__ void vq_prepack(const float* __restrict__ emb, unsigned short* __restrict__ packed) {
    const int off = blockIdx.x * 256 + threadIdx.x;   // 0..262143
    const int j   = off & 7;
    const int col = (off >> 3) & 15;
    const int g   = (off >> 7) & 3;
    const int ds  = (off >> 9) & 7;
    const int cgp = (off >> 12) & 3;
    const int ch  = off >> 14;
    const int code = ch * 64 + cgp * 16 + col;
    const int k    = ds * 32 + g * 8 + j;
    packed[off] = f2bf(emb[code * NC + k]);
}

// ---------- e_norm ----------
__global__ void vq_enorm(const float* __restrict__ emb, float* __restrict__ enorm) {
    int k = blockIdx.x * 256 + threadIdx.x;
    if (k >= NK) return;
    const float4* row = (const float4*)(emb + (size_t)k * NC);
    float s = 0.f;
#pragma unroll
    for (int i = 0; i < NC / 4; ++i) {
        float4 v = row[i];
        s = fmaf(v.x, v.x, fmaf(v.y, v.y, fmaf(v.z, v.z, fmaf(v.w, v.w, s))));
    }
    enorm[k] = s;
}

// ---------- main ----------
__global__ __launch_bounds__(256, 2)
void vq_main(const float* __restrict__ x, const float* __restrict__ emb,
             const unsigned short* __restrict__ packed, const float* __restrict__ enorm_g,
             float* __restrict__ out, float* __restrict__ partials)
{
    __shared__ __align__(16) char LDS[66432];
    char*  Xb   = LDS;                       // [64 r][512 B] bf16 XOR-swz, 32 KiB (dies after af build)
    float* enl  = (float*)(LDS + 32768);     // [1024] (dies after K-loop)
    float* redv = (float*)(LDS + 36864);     // [4][64]
    int*   redi = (int*)(LDS + 37888);       // [4][64]
    float* Qt   = (float*)LDS;               // [64][258] f32 overlay = 66048 B
    int*   widx = (int*)(LDS + 66048);       // [64]
    float* wsum = (float*)(LDS + 66304);     // [4]

    const int tid  = threadIdx.x;
    const int blk  = blockIdx.x;
    const int b    = blk >> 6;                 // 64 tiles of 64 hw per image
    const int hw0  = (blk & 63) << 6;
    const int wv   = tid >> 6;                 // wave = code-group (4 x 16 codes)
    const int lane = tid & 63;
    const int col  = lane & 15;
    const int g    = lane >> 4;

    // ---- stage x -> Xb[r][c] bf16, XOR-swizzled, via ds_write_b128 + sum x^2 ----
    float xsq = 0.f;
#pragma unroll
    for (int it = 0; it < 2; ++it) {
        const int id = tid + (it << 8);        // 0..511 tile id
        const int r4 = (id & 15) << 2;
        const int c0 = (id >> 4) << 3;         // 0..248 step 8
        float4 va[8];
#pragma unroll
        for (int cq = 0; cq < 8; ++cq) {
            va[cq] = *(const float4*)(x + (size_t)(b * NC + c0 + cq) * NHW + hw0 + r4);
            xsq = fmaf(va[cq].x, va[cq].x, fmaf(va[cq].y, va[cq].y,
                  fmaf(va[cq].z, va[cq].z, fmaf(va[cq].w, va[cq].w, xsq))));
        }
#pragma unroll
        for (int q = 0; q < 4; ++q) {
            const int r = r4 + q;
            u16x8 h;
#pragma unroll
            for (int cq = 0; cq < 8; ++cq)
                h[cq] = f2bf(((const float*)&va[cq])[q]);
            *(u16x8*)(Xb + r * 512 + ((c0 * 2) ^ ((r & 15) << 4))) = h;
        }
    }
    *(float4*)&enl[tid << 2] = *(const float4*)&enorm_g[tid << 2];
#pragma unroll
    for (int o = 32; o > 0; o >>= 1) xsq += __shfl_down(xsq, o, 64);
    if (lane == 0) wsum[wv] = xsq;
    __syncthreads();   // Xb + enl visible

    // ---- A fragments -> registers via swizzled ds_read_b128 ----
    // af[mt][ds]: row = mt*16+col, k = ds*32 + g*8 + j
    bf16x8 af[4][8];
#pragma unroll
    for (int mt = 0; mt < 4; ++mt) {
        const int r = (mt << 4) + col;
#pragma unroll
        for (int ds = 0; ds < 8; ++ds)
            af[mt][ds] = *(const bf16x8*)(Xb + r * 512 + (((ds << 6) + (g << 4)) ^ (col << 4)));
    }

    float    bestv[4][4];
    unsigned bc[2] = {0u, 0u};                 // nibble-packed best-chunk ids
#pragma unroll
    for (int mt = 0; mt < 4; ++mt)
#pragma unroll
        for (int q = 0; q < 4; ++q) bestv[mt][q] = 3.4e38f;

    // ---- 16-chunk K-loop: single-buffer B from L2, no LDS staging, no barriers ----
#pragma unroll 1
    for (int ch = 0; ch < NCHUNK; ++ch) {
        const unsigned short* gp = packed + ch * CH_SHORTS + (wv << 12) + (lane << 3);
        bf16x8 bb[8];
#pragma unroll
        for (int ds = 0; ds < 8; ++ds)
            bb[ds] = *(const bf16x8*)(gp + (ds << 9));

        f32x4 ac0 = {0.f,0.f,0.f,0.f}, ac1 = {0.f,0.f,0.f,0.f};
        f32x4 ac2 = {0.f,0.f,0.f,0.f}, ac3 = {0.f,0.f,0.f,0.f};
        __builtin_amdgcn_s_setprio(1);
#pragma unroll
        for (int ds = 0; ds < 8; ++ds) {
            ac0 = __builtin_amdgcn_mfma_f32_16x16x32_bf16(af[0][ds], bb[ds], ac0, 0, 0, 0);
            ac1 = __builtin_amdgcn_mfma_f32_16x16x32_bf16(af[1][ds], bb[ds], ac1, 0, 0, 0);
            ac2 = __builtin_amdgcn_mfma_f32_16x16x32_bf16(af[2][ds], bb[ds], ac2, 0, 0, 0);
            ac3 = __builtin_amdgcn_mfma_f32_16x16x32_bf16(af[3][ds], bb[ds], ac3, 0, 0, 0);
        }
        __builtin_amdgcn_s_setprio(0);

        const float en = enl[(ch << 6) + (wv << 4) + col];
#pragma unroll
        for (int mt = 0; mt < 4; ++mt) {
            const f32x4 a = (mt == 0) ? ac0 : (mt == 1) ? ac1 : (mt == 2) ? ac2 : ac3;
#pragma unroll
            for (int q = 0; q < 4; ++q) {
                const float dist = fmaf(-2.f, a[q], en);   // ||e||^2 - 2 x.e
                const int sh = (((mt & 1) << 2) + q) << 2;
                const unsigned nb = (bc[mt >> 1] & ~(0xFu << sh)) | ((unsigned)ch << sh);
                if (dist < bestv[mt][q]) { bestv[mt][q] = dist; bc[mt >> 1] = nb; }
            }
        }
    }

    // ---- reconstruct indices; cross-lane argmin over the 16 col-lanes ----
    int besti[4][4];
#pragma unroll
    for (int mt = 0; mt < 4; ++mt)
#pragma unroll
        for (int q = 0; q < 4; ++q) {
            const int sh = (((mt & 1) << 2) + q) << 2;
            besti[mt][q] = (int)(((bc[mt >> 1] >> sh) & 15u) << 6) + (wv << 4) + col;
        }
#pragma unroll
    for (int m = 1; m <= 8; m <<= 1) {
#pragma unroll
        for (int mt = 0; mt < 4; ++mt)
#pragma unroll
            for (int q = 0; q < 4; ++q) {
                const float ov = __shfl_xor(bestv[mt][q], m, 64);
                const int   oi = __shfl_xor(besti[mt][q], m, 64);
                if (ov < bestv[mt][q] || (ov == bestv[mt][q] && oi < besti[mt][q])) {
                    bestv[mt][q] = ov; besti[mt][q] = oi;
                }
            }
    }

    // ---- cross-wave argmin (4 code-group waves) + loss partial ----
    if (col == 0) {
#pragma unroll
        for (int mt = 0; mt < 4; ++mt)
#pragma unroll
            for (int q = 0; q < 4; ++q) {
                const int r = (mt << 4) + (g << 2) + q;
                redv[(wv << 6) + r] = bestv[mt][q];
                redi[(wv << 6) + r] = besti[mt][q];
            }
    }
    __syncthreads();
    if (tid < 64) {
        float bv = redv[tid]; int bi = redi[tid];
#pragma unroll
        for (int w = 1; w < 4; ++w) {
            const float v = redv[(w << 6) + tid];
            const int   i = redi[(w << 6) + tid];
            if (v < bv || (v == bv && i < bi)) { bv = v; bi = i; }
        }
        widx[tid] = bi;
        float bsum = bv;   // min dist = ||e||^2 - 2 x.e
#pragma unroll
        for (int o = 32; o > 0; o >>= 1) bsum += __shfl_down(bsum, o, 64);
        if (tid == 0)
            partials[blk] = bsum + wsum[0] + wsum[1] + wsum[2] + wsum[3];  // + sum x^2
    }
    __syncthreads();   // widx ready; all waves past enl/red reads -> Qt overlay safe

    // ---- gather e-rows coalesced -> Qt fp32 (exact), transposed coalesced write ----
#pragma unroll
    for (int rr = 0; rr < 16; ++rr) {
        const int r  = (wv << 4) + rr;
        const int ki = widx[r];                         // wave-uniform broadcast
        const float4 ev = *(const float4*)(emb + (size_t)ki * NC + (lane << 2));
        float* qp = &Qt[r * QTS + (lane << 2)];
        *(float2*)qp       = {ev.x, ev.y};
        *(float2*)(qp + 2) = {ev.z, ev.w};
    }
    __syncthreads();
#pragma unroll 8
    for (int cc = 0; cc < 64; ++cc) {
        const int c = (wv << 6) + cc;
        out[(size_t)(b * NC + c) * NHW + hw0 + lane] = Qt[lane * QTS + c];
    }
}

// ---------- final loss reduction ----------
__global__ void vq_loss_final(const float* __restrict__ partials, float* __restrict__ out_loss) {
    __shared__ float sdata[256];
    float s = 0.f;
    for (int i = threadIdx.x; i < NBLK; i += 256) s += partials[i];
    sdata[threadIdx.x] = s;
    __syncthreads();
    for (int off = 128; off > 0; off >>= 1) {
        if (threadIdx.x < off) sdata[threadIdx.x] += sdata[threadIdx.x + off];
        __syncthreads();
    }
    if (threadIdx.x == 0)
        out_loss[0] = 1.25f * sdata[0] / (float)NUMEL;
}

extern "C" void kernel_launch(void* const* d_in, const int* in_sizes, int n_in,
                              void* d_out, int out_size, void* d_ws, size_t ws_size,
                              hipStream_t stream) {
    const float* x   = (const float*)d_in[0];
    const float* emb = (const float*)d_in[1];
    float* out = (float*)d_out;                              // [NUMEL] quantized + [1] loss
    char*  ws  = (char*)d_ws;
    float* partials = (float*)ws;                            // 2048 floats @ 0
    float* enorm    = (float*)(ws + 8192);                   // 1024 floats
    unsigned short* packed = (unsigned short*)(ws + 12288);  // 512 KiB frag-packed emb

    hipLaunchKernelGGL(vq_prepack, dim3(NK * NC / 256), dim3(256), 0, stream, emb, packed);
    hipLaunchKernelGGL(vq_enorm, dim3(NK / 256), dim3(256), 0, stream, emb, enorm);
    hipLaunchKernelGGL(vq_main, dim3(NBLK), dim3(256), 0, stream, x, emb, packed, enorm, out, partials);
    hipLaunchKernelGGL(vq_loss_final, dim3(1), dim3(256), 0, stream, partials, out + NUMEL);
}

// Round 6
// 141.483 us; speedup vs baseline: 1.1381x; 1.1005x over previous
//
#include <hip/hip_runtime.h>

typedef float  f32x4  __attribute__((ext_vector_type(4)));
typedef __bf16 bf16x8 __attribute__((ext_vector_type(8)));
typedef unsigned short u16x8 __attribute__((ext_vector_type(8)));

#define NB 32
#define NC 256
#define NHW 4096                  // 64*64
#define NN (NB*NHW)               // 131072 rows
#define NK 1024                   // codes
#define NUMEL ((size_t)NN*NC)     // 33554432
#define BM 64                     // rows per block
#define NBLK (NN/BM)              // 2048 blocks
#define NCHUNK 16                 // 64 codes per chunk
#define CH_SHORTS 16384           // 64 codes * 256 k
#define QTS 258                   // Qt row stride (floats)

static __device__ __forceinline__ unsigned short f2bf(float f) {
    unsigned u = __builtin_bit_cast(unsigned, f);
    return (unsigned short)((u + 0x7fffu + ((u >> 16) & 1u)) >> 16);
}

// ---------- prepack emb fp32 -> fragment-linear bf16 ----------
// off = [ch 4b][cgp 2b][ds 3b][g 2b][col 4b][j 3b]
// code = ch*64 + cgp*16 + col ; k = ds*32 + g*8 + j
__global__ void vq_prepack(const float* __restrict__ emb, unsigned short* __restrict__ packed) {
    const int off = blockIdx.x * 256 + threadIdx.x;   // 0..262143
    const int j   = off & 7;
    const int col = (off >> 3) & 15;
    const int g   = (off >> 7) & 3;
    const int ds  = (off >> 9) & 7;
    const int cgp = (off >> 12) & 3;
    const int ch  = off >> 14;
    const int code = ch * 64 + cgp * 16 + col;
    const int k    = ds * 32 + g * 8 + j;
    packed[off] = f2bf(emb[code * NC + k]);
}

// ---------- e_norm ----------
__global__ void vq_enorm(const float* __restrict__ emb, float* __restrict__ enorm) {
    int k = blockIdx.x * 256 + threadIdx.x;
    if (k >= NK) return;
    const float4* row = (const float4*)(emb + (size_t)k * NC);
    float s = 0.f;
#pragma unroll
    for (int i = 0; i < NC / 4; ++i) {
        float4 v = row[i];
        s = fmaf(v.x, v.x, fmaf(v.y, v.y, fmaf(v.z, v.z, fmaf(v.w, v.w, s))));
    }
    enorm[k] = s;
}

// ---------- main: 512 threads = 8 waves = 4 code-groups x 2 row-halves ----------
__global__ __launch_bounds__(512, 4)
void vq_main(const float* __restrict__ x, const float* __restrict__ emb,
             const unsigned short* __restrict__ packed, const float* __restrict__ enorm_g,
             float* __restrict__ out, float* __restrict__ partials)
{
    __shared__ __align__(16) char LDS[66560];
    char*  Xb   = LDS;                       // [64 r][512 B] bf16 XOR-swz, 32 KiB (dies after af build)
    float* enl  = (float*)(LDS + 32768);     // [1024] (dies after K-loop)
    float* redv = (float*)(LDS + 36864);     // [4][64]
    int*   redi = (int*)(LDS + 37888);       // [4][64]
    float* Qt   = (float*)LDS;               // [64][258] f32 overlay = 66048 B
    int*   widx = (int*)(LDS + 66048);       // [64]
    float* wsum = (float*)(LDS + 66304);     // [8]

    const int tid  = threadIdx.x;
    const int blk  = blockIdx.x;
    const int b    = blk >> 6;                 // 64 tiles of 64 hw per image
    const int hw0  = (blk & 63) << 6;
    const int wv   = tid >> 6;
    const int lane = tid & 63;
    const int cg   = wv & 3;                   // code group (16 codes per chunk)
    const int rh   = wv >> 2;                  // row half (rows rh*32 .. rh*32+31)
    const int col  = lane & 15;
    const int g    = lane >> 4;

    // ---- stage x -> Xb[r][c] bf16, XOR-swizzled, via ds_write_b128 + sum x^2 ----
    float xsq = 0.f;
    {
        const int r4 = (tid & 15) << 2;
        const int c0 = (tid >> 4) << 3;        // 0..248 step 8
        float4 va[8];
#pragma unroll
        for (int cq = 0; cq < 8; ++cq) {
            va[cq] = *(const float4*)(x + (size_t)(b * NC + c0 + cq) * NHW + hw0 + r4);
            xsq = fmaf(va[cq].x, va[cq].x, fmaf(va[cq].y, va[cq].y,
                  fmaf(va[cq].z, va[cq].z, fmaf(va[cq].w, va[cq].w, xsq))));
        }
#pragma unroll
        for (int q = 0; q < 4; ++q) {
            const int r = r4 + q;
            u16x8 h;
#pragma unroll
            for (int cq = 0; cq < 8; ++cq)
                h[cq] = f2bf(((const float*)&va[cq])[q]);
            *(u16x8*)(Xb + r * 512 + ((c0 * 2) ^ ((r & 15) << 4))) = h;
        }
    }
    if (tid < 256) *(float4*)&enl[tid << 2] = *(const float4*)&enorm_g[tid << 2];
#pragma unroll
    for (int o = 32; o > 0; o >>= 1) xsq += __shfl_down(xsq, o, 64);
    if (lane == 0) wsum[wv] = xsq;
    __syncthreads();   // Xb + enl visible

    // ---- A fragments -> registers via swizzled ds_read_b128 ----
    // af[mt][ds]: row = rh*32 + mt*16 + col, k = ds*32 + g*8 + j   (64 VGPR)
    bf16x8 af[2][8];
#pragma unroll
    for (int mt = 0; mt < 2; ++mt) {
        const int r = (rh << 5) + (mt << 4) + col;
#pragma unroll
        for (int ds = 0; ds < 8; ++ds)
            af[mt][ds] = *(const bf16x8*)(Xb + r * 512 + (((ds << 6) + (g << 4)) ^ (col << 4)));
    }

    float    bestv[2][4];
    unsigned bc = 0u;                          // nibble-packed best-chunk ids (8 slots)
#pragma unroll
    for (int mt = 0; mt < 2; ++mt)
#pragma unroll
        for (int q = 0; q < 4; ++q) bestv[mt][q] = 3.4e38f;

    // ---- 16-chunk K-loop: B direct from L2 into regs, no LDS staging, no barriers ----
#pragma unroll 1
    for (int ch = 0; ch < NCHUNK; ++ch) {
        const unsigned short* gp = packed + ch * CH_SHORTS + (cg << 12) + (lane << 3);
        bf16x8 bb[8];
#pragma unroll
        for (int ds = 0; ds < 8; ++ds)
            bb[ds] = *(const bf16x8*)(gp + (ds << 9));

        f32x4 ac0 = {0.f,0.f,0.f,0.f}, ac1 = {0.f,0.f,0.f,0.f};
        __builtin_amdgcn_s_setprio(1);
#pragma unroll
        for (int ds = 0; ds < 8; ++ds) {
            ac0 = __builtin_amdgcn_mfma_f32_16x16x32_bf16(af[0][ds], bb[ds], ac0, 0, 0, 0);
            ac1 = __builtin_amdgcn_mfma_f32_16x16x32_bf16(af[1][ds], bb[ds], ac1, 0, 0, 0);
        }
        __builtin_amdgcn_s_setprio(0);

        const float en = enl[(ch << 6) + (cg << 4) + col];
#pragma unroll
        for (int mt = 0; mt < 2; ++mt) {
            const f32x4 a = mt ? ac1 : ac0;
#pragma unroll
            for (int q = 0; q < 4; ++q) {
                const float dist = fmaf(-2.f, a[q], en);   // ||e||^2 - 2 x.e
                const int sh = ((mt << 2) + q) << 2;
                const unsigned nb = (bc & ~(0xFu << sh)) | ((unsigned)ch << sh);
                if (dist < bestv[mt][q]) { bestv[mt][q] = dist; bc = nb; }
            }
        }
    }

    // ---- reconstruct indices; cross-lane argmin over the 16 col-lanes ----
    int besti[2][4];
#pragma unroll
    for (int mt = 0; mt < 2; ++mt)
#pragma unroll
        for (int q = 0; q < 4; ++q) {
            const int sh = ((mt << 2) + q) << 2;
            besti[mt][q] = (int)(((bc >> sh) & 15u) << 6) + (cg << 4) + col;
        }
#pragma unroll
    for (int m = 1; m <= 8; m <<= 1) {
#pragma unroll
        for (int mt = 0; mt < 2; ++mt)
#pragma unroll
            for (int q = 0; q < 4; ++q) {
                const float ov = __shfl_xor(bestv[mt][q], m, 64);
                const int   oi = __shfl_xor(besti[mt][q], m, 64);
                if (ov < bestv[mt][q] || (ov == bestv[mt][q] && oi < besti[mt][q])) {
                    bestv[mt][q] = ov; besti[mt][q] = oi;
                }
            }
    }

    // ---- cross-wave argmin (4 code-group waves per row-half) + loss partial ----
    if (col == 0) {
#pragma unroll
        for (int mt = 0; mt < 2; ++mt)
#pragma unroll
            for (int q = 0; q < 4; ++q) {
                const int r = (rh << 5) + (mt << 4) + (g << 2) + q;   // global row 0..63
                redv[(cg << 6) + r] = bestv[mt][q];
                redi[(cg << 6) + r] = besti[mt][q];
            }
    }
    __syncthreads();
    if (tid < 64) {
        float bv = redv[tid]; int bi = redi[tid];
#pragma unroll
        for (int w = 1; w < 4; ++w) {
            const float v = redv[(w << 6) + tid];
            const int   i = redi[(w << 6) + tid];
            if (v < bv || (v == bv && i < bi)) { bv = v; bi = i; }
        }
        widx[tid] = bi;
        float bsum = bv;   // min dist = ||e||^2 - 2 x.e
#pragma unroll
        for (int o = 32; o > 0; o >>= 1) bsum += __shfl_down(bsum, o, 64);
        if (tid == 0) {
            float s = bsum;
#pragma unroll
            for (int w = 0; w < 8; ++w) s += wsum[w];   // + sum x^2
            partials[blk] = s;                           // = sum ||e - x||^2
        }
    }
    __syncthreads();   // widx ready; all waves done with enl/red -> Qt overlay safe

    // ---- gather e-rows coalesced -> Qt fp32 (exact), transposed coalesced write ----
#pragma unroll
    for (int rr = 0; rr < 8; ++rr) {
        const int r  = (wv << 3) + rr;
        const int ki = widx[r];                         // wave-uniform broadcast
        const float4 ev = *(const float4*)(emb + (size_t)ki * NC + (lane << 2));
        float* qp = &Qt[r * QTS + (lane << 2)];
        *(float2*)qp       = {ev.x, ev.y};
        *(float2*)(qp + 2) = {ev.z, ev.w};
    }
    __syncthreads();
#pragma unroll 8
    for (int cc = 0; cc < 32; ++cc) {
        const int c = (wv << 5) + cc;
        out[(size_t)(b * NC + c) * NHW + hw0 + lane] = Qt[lane * QTS + c];
    }
}

// ---------- final loss reduction ----------
__global__ void vq_loss_final(const float* __restrict__ partials, float* __restrict__ out_loss) {
    __shared__ float sdata[256];
    float s = 0.f;
    for (int i = threadIdx.x; i < NBLK; i += 256) s += partials[i];
    sdata[threadIdx.x] = s;
    __syncthreads();
    for (int off = 128; off > 0; off >>= 1) {
        if (threadIdx.x < off) sdata[threadIdx.x] += sdata[threadIdx.x + off];
        __syncthreads();
    }
    if (threadIdx.x == 0)
        out_loss[0] = 1.25f * sdata[0] / (float)NUMEL;
}

extern "C" void kernel_launch(void* const* d_in, const int* in_sizes, int n_in,
                              void* d_out, int out_size, void* d_ws, size_t ws_size,
                              hipStream_t stream) {
    const float* x   = (const float*)d_in[0];
    const float* emb = (const float*)d_in[1];
    float* out = (float*)d_out;                              // [NUMEL] quantized + [1] loss
    char*  ws  = (char*)d_ws;
    float* partials = (float*)ws;                            // 2048 floats @ 0
    float* enorm    = (float*)(ws + 8192);                   // 1024 floats
    unsigned short* packed = (unsigned short*)(ws + 12288);  // 512 KiB frag-packed emb

    hipLaunchKernelGGL(vq_prepack, dim3(NK * NC / 256), dim3(256), 0, stream, emb, packed);
    hipLaunchKernelGGL(vq_enorm, dim3(NK / 256), dim3(256), 0, stream, emb, enorm);
    hipLaunchKernelGGL(vq_main, dim3(NBLK), dim3(512), 0, stream, x, emb, packed, enorm, out, partials);
    hipLaunchKernelGGL(vq_loss_final, dim3(1), dim3(256), 0, stream, partials, out + NUMEL);
}

// Round 7
// 134.782 us; speedup vs baseline: 1.1946x; 1.0497x over previous
//
#include <hip/hip_runtime.h>

typedef float  f32x4  __attribute__((ext_vector_type(4)));
typedef __bf16 bf16x8 __attribute__((ext_vector_type(8)));
typedef unsigned short u16x8 __attribute__((ext_vector_type(8)));

#define NB 32
#define NC 256
#define NHW 4096                  // 64*64
#define NN (NB*NHW)               // 131072 rows
#define NK 1024                   // codes
#define NUMEL ((size_t)NN*NC)     // 33554432
#define BM 64                     // rows per block
#define NBLK (NN/BM)              // 2048 blocks
#define NCHUNK 32                 // 32 codes per chunk
#define CH_SHORTS 8192            // 32 codes * 256 k
#define QTS 258                   // Qt row stride (floats)

static __device__ __forceinline__ unsigned short f2bf(float f) {
    unsigned u = __builtin_bit_cast(unsigned, f);
    return (unsigned short)((u + 0x7fffu + ((u >> 16) & 1u)) >> 16);
}

// ---------- prepack emb fp32 -> fragment-linear bf16 ----------
// off = [ch 5b][cgp 1b][ds 3b][g 2b][col 4b][j 3b]
// code = ch*32 + cgp*16 + col ; k = ds*32 + g*8 + j
__global__ void vq_prepack(const float* __restrict__ emb, unsigned short* __restrict__ packed) {
    const int off = blockIdx.x * 256 + threadIdx.x;   // 0..262143
    const int j   = off & 7;
    const int col = (off >> 3) & 15;
    const int g   = (off >> 7) & 3;
    const int ds  = (off >> 9) & 7;
    const int cgp = (off >> 12) & 1;
    const int ch  = off >> 13;
    const int code = ch * 32 + cgp * 16 + col;
    const int k    = ds * 32 + g * 8 + j;
    packed[off] = f2bf(emb[code * NC + k]);
}

// ---------- enorm2[k] = -0.5 * sum_c emb[k,c]^2  (MFMA C-init folds the subtraction) ----------
__global__ void vq_enorm(const float* __restrict__ emb, float* __restrict__ enorm2) {
    int k = blockIdx.x * 256 + threadIdx.x;
    if (k >= NK) return;
    const float4* row = (const float4*)(emb + (size_t)k * NC);
    float s = 0.f;
#pragma unroll
    for (int i = 0; i < NC / 4; ++i) {
        float4 v = row[i];
        s = fmaf(v.x, v.x, fmaf(v.y, v.y, fmaf(v.z, v.z, fmaf(v.w, v.w, s))));
    }
    enorm2[k] = -0.5f * s;
}

// ---------- kernel A: distances + argmin (256 thr = 4 waves; 4 blocks/CU) ----------
// wave = (rh, cg): rh = row half (32 rows), cg = 16-code group within 32-code chunk
__global__ __launch_bounds__(256, 4)
void vq_dist(const float* __restrict__ x, const unsigned short* __restrict__ packed,
             const float* __restrict__ enorm2, unsigned short* __restrict__ widx_g,
             float* __restrict__ partials)
{
    __shared__ __align__(16) char LDS[37408];
    char*  Xb   = LDS;                       // [64 r][512 B] bf16 XOR-swz, 32 KiB
    float* enl2 = (float*)(LDS + 32768);     // [1024]
    float* redv = (float*)(LDS + 36864);     // [2][64] packed floats (id in low bits)
    float* wsum = (float*)(LDS + 37376);     // [4]

    const int tid  = threadIdx.x;
    const int blk  = blockIdx.x;
    const int b    = blk >> 6;
    const int hw0  = (blk & 63) << 6;
    const int wv   = tid >> 6;
    const int lane = tid & 63;
    const int cg   = wv & 1;                   // 16-code group
    const int rh   = wv >> 1;                  // row half
    const int col  = lane & 15;
    const int g    = lane >> 4;

    // ---- stage x -> Xb[r][c] bf16 XOR-swz (ds_write_b128) + sum x^2 ----
    float xsq = 0.f;
#pragma unroll
    for (int it = 0; it < 2; ++it) {
        const int id = tid + (it << 8);        // 0..511
        const int r4 = (id & 15) << 2;
        const int c0 = (id >> 4) << 3;
        float4 va[8];
#pragma unroll
        for (int cq = 0; cq < 8; ++cq) {
            va[cq] = *(const float4*)(x + (size_t)(b * NC + c0 + cq) * NHW + hw0 + r4);
            xsq = fmaf(va[cq].x, va[cq].x, fmaf(va[cq].y, va[cq].y,
                  fmaf(va[cq].z, va[cq].z, fmaf(va[cq].w, va[cq].w, xsq))));
        }
#pragma unroll
        for (int q = 0; q < 4; ++q) {
            const int r = r4 + q;
            u16x8 h;
#pragma unroll
            for (int cq = 0; cq < 8; ++cq)
                h[cq] = f2bf(((const float*)&va[cq])[q]);
            *(u16x8*)(Xb + r * 512 + ((c0 * 2) ^ ((r & 15) << 4))) = h;
        }
    }
    *(float4*)&enl2[tid << 2] = *(const float4*)&enorm2[tid << 2];
#pragma unroll
    for (int o = 32; o > 0; o >>= 1) xsq += __shfl_down(xsq, o, 64);
    if (lane == 0) wsum[wv] = xsq;
    __syncthreads();

    // ---- A fragments: row = rh*32 + mt*16 + col, k = ds*32+g*8+j  (64 VGPR) ----
    bf16x8 af[2][8];
#pragma unroll
    for (int mt = 0; mt < 2; ++mt) {
        const int r = (rh << 5) + (mt << 4) + col;
#pragma unroll
        for (int ds = 0; ds < 8; ++ds)
            af[mt][ds] = *(const bf16x8*)(Xb + r * 512 + (((ds << 6) + (g << 4)) ^ (col << 4)));
    }

    float bestv[2][4];
#pragma unroll
    for (int mt = 0; mt < 2; ++mt)
#pragma unroll
        for (int q = 0; q < 4; ++q) bestv[mt][q] = -3.4e38f;   // maximizing s - ||e||^2/2

    // ---- K-loop: half-chunk register double-buffer, no barriers ----
    const unsigned short* gpb = packed + (cg << 12) + (lane << 3);
    bf16x8 bbA[4], bbB[4];
#pragma unroll
    for (int ds = 0; ds < 4; ++ds) bbA[ds] = *(const bf16x8*)(gpb + (ds << 9));

#pragma unroll 1
    for (int ch = 0; ch < NCHUNK; ++ch) {
        const unsigned short* gp = gpb + ch * CH_SHORTS;
#pragma unroll
        for (int ds = 0; ds < 4; ++ds) bbB[ds] = *(const bf16x8*)(gp + 2048 + (ds << 9));

        const float en = enl2[(ch << 5) + (cg << 4) + col];
        f32x4 ac0 = {en, en, en, en};
        f32x4 ac1 = {en, en, en, en};
        __builtin_amdgcn_s_setprio(1);
#pragma unroll
        for (int ds = 0; ds < 4; ++ds) {
            ac0 = __builtin_amdgcn_mfma_f32_16x16x32_bf16(af[0][ds], bbA[ds], ac0, 0, 0, 0);
            ac1 = __builtin_amdgcn_mfma_f32_16x16x32_bf16(af[1][ds], bbA[ds], ac1, 0, 0, 0);
        }
        __builtin_amdgcn_s_setprio(0);

        const int chn = (ch < NCHUNK - 1) ? (ch + 1) : ch;
        const unsigned short* gpn = gpb + chn * CH_SHORTS;
#pragma unroll
        for (int ds = 0; ds < 4; ++ds) bbA[ds] = *(const bf16x8*)(gpn + (ds << 9));

        __builtin_amdgcn_s_setprio(1);
#pragma unroll
        for (int ds = 0; ds < 4; ++ds) {
            ac0 = __builtin_amdgcn_mfma_f32_16x16x32_bf16(af[0][4 + ds], bbB[ds], ac0, 0, 0, 0);
            ac1 = __builtin_amdgcn_mfma_f32_16x16x32_bf16(af[1][4 + ds], bbB[ds], ac1, 0, 0, 0);
        }
        __builtin_amdgcn_s_setprio(0);

        // tail: val = s - ||e||^2/2 (already in acc); pack chunk-id into low 5 mantissa bits, vmax
#pragma unroll
        for (int mt = 0; mt < 2; ++mt) {
            const f32x4 a = mt ? ac1 : ac0;
#pragma unroll
            for (int q = 0; q < 4; ++q) {
                unsigned u = (__builtin_bit_cast(unsigned, a[q]) & 0xFFFFFFE0u) | (unsigned)ch;
                bestv[mt][q] = fmaxf(bestv[mt][q], __builtin_bit_cast(float, u));
            }
        }
    }

    // ---- rebuild full 10-bit code id in low mantissa bits ----
#pragma unroll
    for (int mt = 0; mt < 2; ++mt)
#pragma unroll
        for (int q = 0; q < 4; ++q) {
            unsigned u = __builtin_bit_cast(unsigned, bestv[mt][q]);
            const unsigned id = ((u & 31u) << 5) | ((unsigned)cg << 4) | (unsigned)col;
            u = (u & 0xFFFFFC00u) | id;
            bestv[mt][q] = __builtin_bit_cast(float, u);
        }

    // ---- cross-lane argmax over the 16 col-lanes (id travels inside float) ----
#pragma unroll
    for (int m = 1; m <= 8; m <<= 1)
#pragma unroll
        for (int mt = 0; mt < 2; ++mt)
#pragma unroll
            for (int q = 0; q < 4; ++q)
                bestv[mt][q] = fmaxf(bestv[mt][q], __shfl_xor(bestv[mt][q], m, 64));

    // ---- cross-wave (cg) argmax + widx + loss partial ----
    if (col == 0) {
#pragma unroll
        for (int mt = 0; mt < 2; ++mt)
#pragma unroll
            for (int q = 0; q < 4; ++q)
                redv[(cg << 6) + (rh << 5) + (mt << 4) + (g << 2) + q] = bestv[mt][q];
    }
    __syncthreads();
    if (tid < 64) {
        const float w = fmaxf(redv[tid], redv[64 + tid]);
        const unsigned u = __builtin_bit_cast(unsigned, w);
        widx_g[blk * 64 + tid] = (unsigned short)(u & 1023u);
        // min-dist = ||e||^2 - 2 x.e = -2 * val   (clear id bits for the value)
        const float val = __builtin_bit_cast(float, u & 0xFFFFFC00u);
        float bsum = -2.f * val;
#pragma unroll
        for (int o = 32; o > 0; o >>= 1) bsum += __shfl_down(bsum, o, 64);
        if (tid == 0)
            partials[blk] = bsum + wsum[0] + wsum[1] + wsum[2] + wsum[3];  // + sum x^2
    }
}

// ---------- kernel B: gather + transposed coalesced write (pure BW) ----------
__global__ __launch_bounds__(512, 2)
void vq_scatter(const float* __restrict__ emb, const unsigned short* __restrict__ widx_g,
                float* __restrict__ out)
{
    __shared__ __align__(16) char LDS[66304];
    float* Qt   = (float*)LDS;               // [64][258]
    int*   widx = (int*)(LDS + 66048);       // [64]

    const int tid  = threadIdx.x;
    const int blk  = blockIdx.x;
    const int b    = blk >> 6;
    const int hw0  = (blk & 63) << 6;
    const int wv   = tid >> 6;
    const int lane = tid & 63;

    if (tid < 64) widx[tid] = (int)widx_g[blk * 64 + tid];
    __syncthreads();

#pragma unroll
    for (int rr = 0; rr < 8; ++rr) {
        const int r  = (wv << 3) + rr;
        const int ki = widx[r];                         // wave-uniform broadcast
        const float4 ev = *(const float4*)(emb + (size_t)ki * NC + (lane << 2));
        float* qp = &Qt[r * QTS + (lane << 2)];
        *(float2*)qp       = {ev.x, ev.y};
        *(float2*)(qp + 2) = {ev.z, ev.w};
    }
    __syncthreads();
#pragma unroll 8
    for (int cc = 0; cc < 32; ++cc) {
        const int c = (wv << 5) + cc;
        out[(size_t)(b * NC + c) * NHW + hw0 + lane] = Qt[lane * QTS + c];
    }
}

// ---------- final loss reduction ----------
__global__ void vq_loss_final(const float* __restrict__ partials, float* __restrict__ out_loss) {
    __shared__ float sdata[256];
    float s = 0.f;
    for (int i = threadIdx.x; i < NBLK; i += 256) s += partials[i];
    sdata[threadIdx.x] = s;
    __syncthreads();
    for (int off = 128; off > 0; off >>= 1) {
        if (threadIdx.x < off) sdata[threadIdx.x] += sdata[threadIdx.x + off];
        __syncthreads();
    }
    if (threadIdx.x == 0)
        out_loss[0] = 1.25f * sdata[0] / (float)NUMEL;
}

extern "C" void kernel_launch(void* const* d_in, const int* in_sizes, int n_in,
                              void* d_out, int out_size, void* d_ws, size_t ws_size,
                              hipStream_t stream) {
    const float* x   = (const float*)d_in[0];
    const float* emb = (const float*)d_in[1];
    float* out = (float*)d_out;                              // [NUMEL] quantized + [1] loss
    char*  ws  = (char*)d_ws;
    float* partials = (float*)ws;                            // 2048 floats            @ 0
    float* enorm2   = (float*)(ws + 8192);                   // 1024 floats            @ 8K
    unsigned short* packed = (unsigned short*)(ws + 12288);  // 512 KiB packed emb     @ 12K
    unsigned short* widx   = (unsigned short*)(ws + 536576); // 256 KiB indices        @ 524K+12K

    hipLaunchKernelGGL(vq_prepack, dim3(NK * NC / 256), dim3(256), 0, stream, emb, packed);
    hipLaunchKernelGGL(vq_enorm, dim3(NK / 256), dim3(256), 0, stream, emb, enorm2);
    hipLaunchKernelGGL(vq_dist, dim3(NBLK), dim3(256), 0, stream, x, packed, enorm2, widx, partials);
    hipLaunchKernelGGL(vq_scatter, dim3(NBLK), dim3(512), 0, stream, emb, widx, out);
    hipLaunchKernelGGL(vq_loss_final, dim3(1), dim3(256), 0, stream, partials, out + NUMEL);
}

// Round 8
// 103.421 us; speedup vs baseline: 1.5569x; 1.3032x over previous
//
#include <hip/hip_runtime.h>

typedef float  f32x4  __attribute__((ext_vector_type(4)));
typedef unsigned long u64;
typedef u64 u64x2 __attribute__((ext_vector_type(2)));

#define NB 32
#define NC 256
#define NHW 4096                  // 64*64
#define NN (NB*NHW)               // 131072 rows
#define NK 1024                   // codes
#define NUMEL ((size_t)NN*NC)     // 33554432
#define BM 64                     // rows per block
#define NBLK (NN/BM)              // 2048 blocks
#define NCHUNK 16                 // 64 codes per chunk
#define CH_BYTES 16384            // 64 codes * 256 k * 1B
#define QTS 258                   // Qt row stride (floats)
#define ESCALE 512.0f             // emb scaled by 512 before fp8 quant

// ---------- prepack emb fp32 -> fragment-linear fp8 (e4m3, scaled x512) ----------
// byte off bits: [ch 4][cg 2][dsp 2][g 2][col 4][dd 1][j 3]
// code = ch*64+cg*16+col ; k = (dsp*2+dd)*32 + g*8 + j
__global__ void vq_prepack(const float* __restrict__ emb, unsigned char* __restrict__ packed) {
    const int base = (blockIdx.x * 256 + threadIdx.x) * 4;   // 4 bytes/thread, same k-quad
    const int j0  = base & 7;          // 0 or 4
    const int dd  = (base >> 3) & 1;
    const int col = (base >> 4) & 15;
    const int g   = (base >> 8) & 3;
    const int dsp = (base >> 10) & 3;
    const int cg  = (base >> 12) & 3;
    const int ch  = base >> 14;
    const int code = ch * 64 + cg * 16 + col;
    const int k    = (dsp * 2 + dd) * 32 + g * 8 + j0;
    const float4 v = *(const float4*)(emb + (size_t)code * NC + k);
    int w = 0;
    w = __builtin_amdgcn_cvt_pk_fp8_f32(v.x * ESCALE, v.y * ESCALE, w, false);
    w = __builtin_amdgcn_cvt_pk_fp8_f32(v.z * ESCALE, v.w * ESCALE, w, true);
    *(int*)(packed + base) = w;
}

// ---------- enorm2[k] = -256 * sum_c emb[k,c]^2  (= -||e_scaled||^2/2, fp32-exact) ----------
__global__ void vq_enorm(const float* __restrict__ emb, float* __restrict__ enorm2) {
    int k = blockIdx.x * 256 + threadIdx.x;
    if (k >= NK) return;
    const float4* row = (const float4*)(emb + (size_t)k * NC);
    float s = 0.f;
#pragma unroll
    for (int i = 0; i < NC / 4; ++i) {
        float4 v = row[i];
        s = fmaf(v.x, v.x, fmaf(v.y, v.y, fmaf(v.z, v.z, fmaf(v.w, v.w, s))));
    }
    enorm2[k] = -256.0f * s;
}

#define MFMA4(K, B)                                                                  \
    a0 = __builtin_amdgcn_mfma_f32_16x16x32_fp8_fp8((long)af[0][K], (long)(B), a0, 0, 0, 0); \
    a1 = __builtin_amdgcn_mfma_f32_16x16x32_fp8_fp8((long)af[1][K], (long)(B), a1, 0, 0, 0); \
    a2 = __builtin_amdgcn_mfma_f32_16x16x32_fp8_fp8((long)af[2][K], (long)(B), a2, 0, 0, 0); \
    a3 = __builtin_amdgcn_mfma_f32_16x16x32_fp8_fp8((long)af[3][K], (long)(B), a3, 0, 0, 0)

#define TAIL(MT, A)                                                                  \
    _Pragma("unroll")                                                                \
    for (int q = 0; q < 4; ++q) {                                                    \
        unsigned u = (__builtin_bit_cast(unsigned, (A)[q]) & 0xFFFFFFF0u) | (unsigned)ch; \
        bestv[MT][q] = fmaxf(bestv[MT][q], __builtin_bit_cast(float, u));            \
    }

// ---------- kernel A: distances + argmin (256 thr = 4 cg-waves over same 64 rows) ----------
__global__ __launch_bounds__(256, 4)
void vq_dist(const float* __restrict__ x, const unsigned char* __restrict__ packed,
             const float* __restrict__ enorm2, unsigned short* __restrict__ widx_g,
             float* __restrict__ partials)
{
    __shared__ __align__(16) char LDS[21536];
    char*  Xb   = LDS;                       // [64 r][256 B] fp8 XOR-swz, 16 KiB
    float* enl2 = (float*)(LDS + 16384);     // [1024]
    float* redv = (float*)(LDS + 20480);     // [4][64] packed floats
    float* wsum = (float*)(LDS + 21504);     // [4]

    const int tid  = threadIdx.x;
    const int blk  = blockIdx.x;
    const int b    = blk >> 6;
    const int hw0  = (blk & 63) << 6;
    const int cg   = tid >> 6;                 // wave = 16-code group
    const int lane = tid & 63;
    const int col  = lane & 15;
    const int g    = lane >> 4;

    // ---- stage x -> Xb[r][c] fp8 (scale 1), XOR-swizzled; + sum x^2 (fp32) ----
    float xsq = 0.f;
#pragma unroll
    for (int it = 0; it < 2; ++it) {
        const int r4 = (tid & 15) << 2;
        const int c0 = (((tid >> 4) & 15) + (it << 4)) << 3;
        float4 va[8];
#pragma unroll
        for (int cq = 0; cq < 8; ++cq) {
            va[cq] = *(const float4*)(x + (size_t)(b * NC + c0 + cq) * NHW + hw0 + r4);
            xsq = fmaf(va[cq].x, va[cq].x, fmaf(va[cq].y, va[cq].y,
                  fmaf(va[cq].z, va[cq].z, fmaf(va[cq].w, va[cq].w, xsq))));
        }
#pragma unroll
        for (int q = 0; q < 4; ++q) {
            const int r = r4 + q;
            int w0 = 0, w1 = 0;
            w0 = __builtin_amdgcn_cvt_pk_fp8_f32(((const float*)&va[0])[q], ((const float*)&va[1])[q], w0, false);
            w0 = __builtin_amdgcn_cvt_pk_fp8_f32(((const float*)&va[2])[q], ((const float*)&va[3])[q], w0, true);
            w1 = __builtin_amdgcn_cvt_pk_fp8_f32(((const float*)&va[4])[q], ((const float*)&va[5])[q], w1, false);
            w1 = __builtin_amdgcn_cvt_pk_fp8_f32(((const float*)&va[6])[q], ((const float*)&va[7])[q], w1, true);
            int2 wp = {w0, w1};
            *(int2*)(Xb + r * 256 + (c0 ^ ((r & 15) << 4))) = wp;
        }
    }
    *(float4*)&enl2[tid << 2] = *(const float4*)&enorm2[tid << 2];
#pragma unroll
    for (int o = 32; o > 0; o >>= 1) xsq += __shfl_down(xsq, o, 64);
    if (lane == 0) wsum[cg] = xsq;
    __syncthreads();

    // ---- A fragments: af[mt][ds] = rows mt*16+col, k = ds*32+g*8+(0..7)  (64 VGPR) ----
    u64 af[4][8];
#pragma unroll
    for (int mt = 0; mt < 4; ++mt) {
        const int r = (mt << 4) + col;
#pragma unroll
        for (int ds = 0; ds < 8; ++ds)
            af[mt][ds] = *(const u64*)(Xb + r * 256 + (((ds << 5) + (g << 3)) ^ (col << 4)));
    }

    float bestv[4][4];
#pragma unroll
    for (int mt = 0; mt < 4; ++mt)
#pragma unroll
        for (int q = 0; q < 4; ++q) bestv[mt][q] = -3.4e38f;   // maximize 512*x.e - 256||e||^2

    // ---- K-loop: fp8 B direct from L2, half-chunk ping-pong, no barriers ----
    const char* gpb = (const char*)packed + (cg << 12) + (lane << 4);
    u64x2 pA0, pA1, pB0, pB1;
    pA0 = *(const u64x2*)(gpb);
    pA1 = *(const u64x2*)(gpb + 1024);

#pragma unroll 1
    for (int ch = 0; ch < NCHUNK; ++ch) {
        const char* gp = gpb + ch * CH_BYTES;
        pB0 = *(const u64x2*)(gp + 2048);
        pB1 = *(const u64x2*)(gp + 3072);

        const float en = enl2[(ch << 6) + (cg << 4) + col];
        f32x4 a0 = {en, en, en, en}, a1 = {en, en, en, en};
        f32x4 a2 = {en, en, en, en}, a3 = {en, en, en, en};

        __builtin_amdgcn_s_setprio(1);
        MFMA4(0, pA0.x); MFMA4(1, pA0.y); MFMA4(2, pA1.x); MFMA4(3, pA1.y);
        __builtin_amdgcn_s_setprio(0);

        const int chn = (ch < NCHUNK - 1) ? (ch + 1) : ch;
        pA0 = *(const u64x2*)(gpb + chn * CH_BYTES);
        pA1 = *(const u64x2*)(gpb + chn * CH_BYTES + 1024);

        __builtin_amdgcn_s_setprio(1);
        MFMA4(4, pB0.x); MFMA4(5, pB0.y); MFMA4(6, pB1.x); MFMA4(7, pB1.y);
        __builtin_amdgcn_s_setprio(0);

        TAIL(0, a0); TAIL(1, a1); TAIL(2, a2); TAIL(3, a3);
    }

    // ---- rebuild 10-bit code id in low mantissa bits ----
#pragma unroll
    for (int mt = 0; mt < 4; ++mt)
#pragma unroll
        for (int q = 0; q < 4; ++q) {
            unsigned u = __builtin_bit_cast(unsigned, bestv[mt][q]);
            const unsigned id = ((u & 15u) << 6) | ((unsigned)cg << 4) | (unsigned)col;
            u = (u & 0xFFFFFC00u) | id;
            bestv[mt][q] = __builtin_bit_cast(float, u);
        }

    // ---- cross-lane argmax over the 16 col-lanes (id travels inside float) ----
#pragma unroll
    for (int m = 1; m <= 8; m <<= 1)
#pragma unroll
        for (int mt = 0; mt < 4; ++mt)
#pragma unroll
            for (int q = 0; q < 4; ++q)
                bestv[mt][q] = fmaxf(bestv[mt][q], __shfl_xor(bestv[mt][q], m, 64));

    // ---- cross-wave (cg) argmax + widx + loss partial ----
    if (col == 0) {
#pragma unroll
        for (int mt = 0; mt < 4; ++mt)
#pragma unroll
            for (int q = 0; q < 4; ++q)
                redv[(cg << 6) + (mt << 4) + (g << 2) + q] = bestv[mt][q];
    }
    __syncthreads();
    if (tid < 64) {
        float w = fmaxf(fmaxf(redv[tid], redv[64 + tid]), fmaxf(redv[128 + tid], redv[192 + tid]));
        const unsigned u = __builtin_bit_cast(unsigned, w);
        widx_g[blk * 64 + tid] = (unsigned short)(u & 1023u);
        // true min-dist part: ||e||^2 - 2 x.e = -val/256 (val = 512 x.e - 256||e||^2)
        const float val = __builtin_bit_cast(float, u & 0xFFFFFC00u);
        float bsum = val * (-1.0f / 256.0f);
#pragma unroll
        for (int o = 32; o > 0; o >>= 1) bsum += __shfl_down(bsum, o, 64);
        if (tid == 0)
            partials[blk] = bsum + wsum[0] + wsum[1] + wsum[2] + wsum[3];  // + sum x^2
    }
}

// ---------- kernel B: gather + transposed coalesced write (L3-absorbed) ----------
__global__ __launch_bounds__(512, 2)
void vq_scatter(const float* __restrict__ emb, const unsigned short* __restrict__ widx_g,
                float* __restrict__ out)
{
    __shared__ __align__(16) char LDS[66304];
    float* Qt   = (float*)LDS;               // [64][258]
    int*   widx = (int*)(LDS + 66048);       // [64]

    const int tid  = threadIdx.x;
    const int blk  = blockIdx.x;
    const int b    = blk >> 6;
    const int hw0  = (blk & 63) << 6;
    const int wv   = tid >> 6;
    const int lane = tid & 63;

    if (tid < 64) widx[tid] = (int)widx_g[blk * 64 + tid];
    __syncthreads();

#pragma unroll
    for (int rr = 0; rr < 8; ++rr) {
        const int r  = (wv << 3) + rr;
        const int ki = widx[r];                         // wave-uniform broadcast
        const float4 ev = *(const float4*)(emb + (size_t)ki * NC + (lane << 2));
        float* qp = &Qt[r * QTS + (lane << 2)];
        *(float2*)qp       = {ev.x, ev.y};
        *(float2*)(qp + 2) = {ev.z, ev.w};
    }
    __syncthreads();
#pragma unroll 8
    for (int cc = 0; cc < 32; ++cc) {
        const int c = (wv << 5) + cc;
        out[(size_t)(b * NC + c) * NHW + hw0 + lane] = Qt[lane * QTS + c];
    }
}

// ---------- final loss reduction ----------
__global__ void vq_loss_final(const float* __restrict__ partials, float* __restrict__ out_loss) {
    __shared__ float sdata[256];
    float s = 0.f;
    for (int i = threadIdx.x; i < NBLK; i += 256) s += partials[i];
    sdata[threadIdx.x] = s;
    __syncthreads();
    for (int off = 128; off > 0; off >>= 1) {
        if (threadIdx.x < off) sdata[threadIdx.x] += sdata[threadIdx.x + off];
        __syncthreads();
    }
    if (threadIdx.x == 0)
        out_loss[0] = 1.25f * sdata[0] / (float)NUMEL;
}

extern "C" void kernel_launch(void* const* d_in, const int* in_sizes, int n_in,
                              void* d_out, int out_size, void* d_ws, size_t ws_size,
                              hipStream_t stream) {
    const float* x   = (const float*)d_in[0];
    const float* emb = (const float*)d_in[1];
    float* out = (float*)d_out;                              // [NUMEL] quantized + [1] loss
    char*  ws  = (char*)d_ws;
    float* partials = (float*)ws;                            // 2048 floats           @ 0
    float* enorm2   = (float*)(ws + 8192);                   // 1024 floats           @ 8K
    unsigned char*  packed = (unsigned char*)(ws + 12288);   // 256 KiB fp8 packed    @ 12K
    unsigned short* widx   = (unsigned short*)(ws + 274432); // 256 KiB indices

    hipLaunchKernelGGL(vq_prepack, dim3(NK * NC / 1024), dim3(256), 0, stream, emb, packed);
    hipLaunchKernelGGL(vq_enorm, dim3(NK / 256), dim3(256), 0, stream, emb, enorm2);
    hipLaunchKernelGGL(vq_dist, dim3(NBLK), dim3(256), 0, stream, x, packed, enorm2, widx, partials);
    hipLaunchKernelGGL(vq_scatter, dim3(NBLK), dim3(512), 0, stream, emb, widx, out);
    hipLaunchKernelGGL(vq_loss_final, dim3(1), dim3(256), 0, stream, partials, out + NUMEL);
}